// Round 1
// 1262.019 us; speedup vs baseline: 1.0069x; 1.0069x over previous
//
#include <hip/hip_runtime.h>

// Segment-mean pooling, two-stage: N=2e6 rows x D=128, G=1024 segments (sorted ids).
//   k0: offs[g] = lower_bound(batch, g) for g in [0, G]   (parallel binary search)
//   k1: grid G*8 blocks; block (g,s) sums its interleaved slice of segment g
//       into partials[(g*8+s)*128 ..] (workspace). 4 float4 loads in flight/thread.
//   k2: grid G blocks; sum 8 partial rows, divide by count, write out.
// Deterministic (no atomics); ws needs 8 KB + G*8*512 B (~4 MB).

#define SPLIT 8

__global__ __launch_bounds__(256) void seg_offsets_kernel(
    const int* __restrict__ batch, int* __restrict__ offs, int N, int G) {
  const int g = blockIdx.x * 256 + threadIdx.x;
  if (g > G) return;
  int lo = 0, hi = N;
  while (lo < hi) {
    const int mid = (lo + hi) >> 1;
    if (batch[mid] < g) lo = mid + 1; else hi = mid;
  }
  offs[g] = lo;  // g == G: all ids < G, so lo == N
}

__global__ __launch_bounds__(256) void seg_partial_kernel(
    const float* __restrict__ h,
    const int* __restrict__ offs,
    float* __restrict__ partials) {
  const int g = blockIdx.x >> 3;   // segment
  const int s = blockIdx.x & 7;    // slice 0..7
  const int start = offs[g];
  const int end   = offs[g + 1];

  const int tid  = threadIdx.x;
  const int c    = tid & 31;       // feature quad: floats [4c, 4c+4)
  const int r    = tid >> 5;       // row slot within slice
  const int slot = s * 8 + r;      // 0..63 within segment

  float4 acc = make_float4(0.f, 0.f, 0.f, 0.f);

  // Thread covers rows start+slot, +64, +128, ... ; wave (r=0,1) reads two
  // consecutive rows per load instruction -> contiguous 1 KB per instr.
  int row = start + slot;
  const float* p = h + (size_t)row * 128 + (size_t)c * 4;

  // 4 independent loads in flight (row stride 64 = 8192 floats = 32 KB).
  for (; row + 192 < end; row += 256, p += 32768) {
    const float4 v0 = *(const float4*)(p);
    const float4 v1 = *(const float4*)(p + 8192);
    const float4 v2 = *(const float4*)(p + 16384);
    const float4 v3 = *(const float4*)(p + 24576);
    acc.x += v0.x + v1.x + v2.x + v3.x;
    acc.y += v0.y + v1.y + v2.y + v3.y;
    acc.z += v0.z + v1.z + v2.z + v3.z;
    acc.w += v0.w + v1.w + v2.w + v3.w;
  }
  for (; row < end; row += 64, p += 8192) {
    const float4 v = *(const float4*)(p);
    acc.x += v.x; acc.y += v.y; acc.z += v.z; acc.w += v.w;
  }

  __shared__ float4 smem[256];
  smem[tid] = acc;
  __syncthreads();

  if (r == 0) {
    float4 sum = smem[c];
    #pragma unroll
    for (int k = 1; k < 8; ++k) {
      const float4 v = smem[k * 32 + c];
      sum.x += v.x; sum.y += v.y; sum.z += v.z; sum.w += v.w;
    }
    *(float4*)(partials + (size_t)blockIdx.x * 128 + (size_t)c * 4) = sum;
  }
}

__global__ __launch_bounds__(256) void seg_final_kernel(
    const float* __restrict__ partials,
    const int* __restrict__ offs,
    float* __restrict__ out) {
  const int g   = blockIdx.x;
  const int tid = threadIdx.x;
  const int c   = tid & 31;
  const int r   = tid >> 5;

  const float4 v =
      *(const float4*)(partials + ((size_t)g * 8 + r) * 128 + (size_t)c * 4);
  __shared__ float4 smem[256];
  smem[tid] = v;
  __syncthreads();

  if (r == 0) {
    float4 sum = smem[c];
    #pragma unroll
    for (int k = 1; k < 8; ++k) {
      const float4 w = smem[k * 32 + c];
      sum.x += w.x; sum.y += w.y; sum.z += w.z; sum.w += w.w;
    }
    const int cnt = offs[g + 1] - offs[g];
    const float inv = 1.0f / (float)(cnt > 0 ? cnt : 1);
    float4 o;
    o.x = sum.x * inv; o.y = sum.y * inv; o.z = sum.z * inv; o.w = sum.w * inv;
    *(float4*)(out + (size_t)g * 128 + (size_t)c * 4) = o;
  }
}

extern "C" void kernel_launch(void* const* d_in, const int* in_sizes, int n_in,
                              void* d_out, int out_size, void* d_ws, size_t ws_size,
                              hipStream_t stream) {
  const float* node_h = (const float*)d_in[0];
  const int*   batch  = (const int*)d_in[1];
  float*       out    = (float*)d_out;

  const int N = in_sizes[1];        // 2,000,000
  const int D = in_sizes[0] / N;    // 128
  const int G = out_size / D;       // 1024

  int*   offs     = (int*)d_ws;                       // G+1 ints
  float* partials = (float*)((char*)d_ws + 8192);     // G*8 rows x 128 floats

  seg_offsets_kernel<<<(G + 1 + 255) / 256, 256, 0, stream>>>(batch, offs, N, G);
  seg_partial_kernel<<<G * SPLIT, 256, 0, stream>>>(node_h, offs, partials);
  seg_final_kernel<<<G, 256, 0, stream>>>(partials, offs, out);
}